// Round 8
// baseline (1122.148 us; speedup 1.0000x reference)
//
#include <hip/hip_runtime.h>

#define NQT   300
#define HWT   4096
#define NHEAD 8
#define HDIM  32
#define QT     16
#define NSUB   5          // 5 sub-tiles of 16 q = 80 q per block
#define QBLK   80
#define TK     128
#define NSPLIT 8
#define KSPLIT 512
#define NQB20  20         // 16-q record blocks allocated (19 valid + 1 pad)
#define RECSZ  544        // 16 m + 16 l + 16*32 acc

// ---------------------------------------------------------------------------
// Fused K+V projection (unchanged from round 2-7 measurement)
// ---------------------------------------------------------------------------
__global__ __launch_bounds__(256, 2) void proj_kv(
    const float* __restrict__ src, const float* __restrict__ pos,
    const float* __restrict__ Wk, const float* __restrict__ bk,
    const float* __restrict__ Wv, const float* __restrict__ bv,
    float* __restrict__ Kout, float* __restrict__ Vout)
{
    __shared__ float As[16][132];   // [k][row]
    const int bid  = blockIdx.x;          // 0..511
    const int xcd  = bid & 7;
    const int idx  = bid >> 3;            // 0..63
    const int mblk = xcd * 8 + (idx >> 3);
    const int sub  = idx & 7;
    const int isV  = sub >> 2;
    const int n0   = (sub & 3) * 64;
    const int m0   = mblk * 128;

    const float* W    = isV ? Wv : Wk;
    const float* bias = isV ? bv : bk;
    float* Out        = isV ? Vout : Kout;

    const int t  = threadIdx.x;
    const int rg = t >> 4, cg = t & 15;
    const int ar = t >> 2, ac4 = t & 3;

    float acc[8][4] = {};

    for (int k0 = 0; k0 < 256; k0 += 16) {
        float4 av[2];
        #pragma unroll
        for (int i = 0; i < 2; ++i) {
            const int row = m0 + ar + 64 * i;
            av[i] = *(const float4*)(src + (size_t)row * 256 + k0 + ac4 * 4);
            if (!isV) {
                float4 pv = *(const float4*)(pos + (size_t)row * 256 + k0 + ac4 * 4);
                av[i].x += pv.x; av[i].y += pv.y; av[i].z += pv.z; av[i].w += pv.w;
            }
        }
        __syncthreads();
        #pragma unroll
        for (int i = 0; i < 2; ++i) {
            const int row = ar + 64 * i;
            As[ac4 * 4 + 0][row] = av[i].x;
            As[ac4 * 4 + 1][row] = av[i].y;
            As[ac4 * 4 + 2][row] = av[i].z;
            As[ac4 * 4 + 3][row] = av[i].w;
        }
        __syncthreads();

        float4 bcur = *(const float4*)(W + (size_t)k0 * 256 + n0 + cg * 4);
        #pragma unroll
        for (int k = 0; k < 16; ++k) {
            float4 bnext;
            if (k < 15)
                bnext = *(const float4*)(W + (size_t)(k0 + k + 1) * 256 + n0 + cg * 4);
            float4 a0 = *(const float4*)&As[k][rg * 8];
            float4 a1 = *(const float4*)&As[k][rg * 8 + 4];
            float a[8] = {a0.x, a0.y, a0.z, a0.w, a1.x, a1.y, a1.z, a1.w};
            float bb[4] = {bcur.x, bcur.y, bcur.z, bcur.w};
            #pragma unroll
            for (int i = 0; i < 8; ++i)
                #pragma unroll
                for (int j = 0; j < 4; ++j)
                    acc[i][j] = fmaf(a[i], bb[j], acc[i][j]);
            if (k < 15) bcur = bnext;
        }
    }

    float4 bb = *(const float4*)(bias + n0 + cg * 4);
    #pragma unroll
    for (int i = 0; i < 8; ++i) {
        const int gr = m0 + rg * 8 + i;
        float4 o;
        o.x = acc[i][0] + bb.x;
        o.y = acc[i][1] + bb.y;
        o.z = acc[i][2] + bb.z;
        o.w = acc[i][3] + bb.w;
        *(float4*)(Out + (size_t)gr * 256 + n0 + cg * 4) = o;
    }
}

// ---------------------------------------------------------------------------
// Small projection (M=600) — unchanged
// ---------------------------------------------------------------------------
__global__ __launch_bounds__(256) void proj_small(
    const float* __restrict__ X, const float* __restrict__ Xpos,
    const float* __restrict__ W, const float* __restrict__ bias,
    float* __restrict__ Out, int M, float scale)
{
    __shared__ float As[16][36];
    const int m0 = blockIdx.x * 32;
    const int n0 = blockIdx.y * 64;
    const int t  = threadIdx.x;
    const int rg = t >> 4, cg = t & 15;

    float acc[2][4] = {};

    for (int k0 = 0; k0 < 256; k0 += 16) {
        float4 av = make_float4(0.f, 0.f, 0.f, 0.f);
        const int ar = t >> 2, ac4 = t & 3;
        if (t < 128) {
            int row = m0 + ar;
            if (row < M) {
                av = *(const float4*)(X + (size_t)row * 256 + k0 + ac4 * 4);
                if (Xpos) {
                    float4 pv = *(const float4*)(Xpos + (size_t)row * 256 + k0 + ac4 * 4);
                    av.x += pv.x; av.y += pv.y; av.z += pv.z; av.w += pv.w;
                }
            }
        }
        __syncthreads();
        if (t < 128) {
            As[ac4 * 4 + 0][ar] = av.x;
            As[ac4 * 4 + 1][ar] = av.y;
            As[ac4 * 4 + 2][ar] = av.z;
            As[ac4 * 4 + 3][ar] = av.w;
        }
        __syncthreads();

        float4 bcur = *(const float4*)(W + (size_t)k0 * 256 + n0 + cg * 4);
        #pragma unroll
        for (int k = 0; k < 16; ++k) {
            float4 bnext;
            if (k < 15)
                bnext = *(const float4*)(W + (size_t)(k0 + k + 1) * 256 + n0 + cg * 4);
            float a0 = As[k][rg * 2], a1 = As[k][rg * 2 + 1];
            acc[0][0] = fmaf(a0, bcur.x, acc[0][0]);
            acc[0][1] = fmaf(a0, bcur.y, acc[0][1]);
            acc[0][2] = fmaf(a0, bcur.z, acc[0][2]);
            acc[0][3] = fmaf(a0, bcur.w, acc[0][3]);
            acc[1][0] = fmaf(a1, bcur.x, acc[1][0]);
            acc[1][1] = fmaf(a1, bcur.y, acc[1][1]);
            acc[1][2] = fmaf(a1, bcur.z, acc[1][2]);
            acc[1][3] = fmaf(a1, bcur.w, acc[1][3]);
            if (k < 15) bcur = bnext;
        }
    }

    float4 bb = *(const float4*)(bias + n0 + cg * 4);
    #pragma unroll
    for (int i = 0; i < 2; ++i) {
        const int gr = m0 + rg * 2 + i;
        if (gr < M) {
            float4 o;
            o.x = (acc[i][0] + bb.x) * scale;
            o.y = (acc[i][1] + bb.y) * scale;
            o.z = (acc[i][2] + bb.z) * scale;
            o.w = (acc[i][3] + bb.w) * scale;
            *(float4*)(Out + (size_t)gr * 256 + n0 + cg * 4) = o;
        }
    }
}

// ---------------------------------------------------------------------------
// RPE tables — unchanged
// ---------------------------------------------------------------------------
__global__ __launch_bounds__(256) void rpe_kernel(
    const float* __restrict__ refpts,
    const float* __restrict__ w1x, const float* __restrict__ b1x, const float* __restrict__ w2x,
    const float* __restrict__ w1y, const float* __restrict__ b1y, const float* __restrict__ w2y,
    float* __restrict__ outx, float* __restrict__ outy)
{
    const int axis = blockIdx.y;
    const int t    = threadIdx.x;
    const int item = blockIdx.x * 128 + (t >> 1);
    const int half = t & 1;
    const int bq   = __builtin_amdgcn_readfirstlane(item >> 6);
    const int pos  = item & 63;

    const float* w1 = axis ? w1y : w1x;
    const float* b1 = axis ? b1y : b1x;
    const float* w2 = axis ? w2y : w2x;

    float4 r = *(const float4*)(refpts + (size_t)bq * 4);
    float ctr  = axis ? r.y : r.x;
    float hlf  = (axis ? r.w : r.z) * 0.5f;
    float lo = (ctr - hlf) * 1024.f;
    float hi = (ctr + hlf) * 1024.f;
    float p  = ((float)pos + 0.5f) * 16.f;
    float d0 = lo - p, d1 = hi - p;

    float a0 = 0.f, a1 = 0.f, a2 = 0.f, a3 = 0.f;
    float a4 = 0.f, a5 = 0.f, a6 = 0.f, a7 = 0.f;

    const int h0 = half * 256;
    #pragma unroll 4
    for (int i = 0; i < 256; ++i) {
        const int hid = h0 + i;
        float hv = fmaf(d0, w1[hid], fmaf(d1, w1[512 + hid], b1[hid]));
        hv = fmaxf(hv, 0.f);
        float4 wA = *(const float4*)(w2 + (size_t)hid * 8);
        float4 wB = *(const float4*)(w2 + (size_t)hid * 8 + 4);
        a0 = fmaf(hv, wA.x, a0); a1 = fmaf(hv, wA.y, a1);
        a2 = fmaf(hv, wA.z, a2); a3 = fmaf(hv, wA.w, a3);
        a4 = fmaf(hv, wB.x, a4); a5 = fmaf(hv, wB.y, a5);
        a6 = fmaf(hv, wB.z, a6); a7 = fmaf(hv, wB.w, a7);
    }
    a0 += __shfl_xor(a0, 1); a1 += __shfl_xor(a1, 1);
    a2 += __shfl_xor(a2, 1); a3 += __shfl_xor(a3, 1);
    a4 += __shfl_xor(a4, 1); a5 += __shfl_xor(a5, 1);
    a6 += __shfl_xor(a6, 1); a7 += __shfl_xor(a7, 1);

    if (half == 0) {
        float* op = (axis ? outy : outx) + (size_t)bq * 512 + pos;
        op[0]   = a0; op[64]  = a1; op[128] = a2; op[192] = a3;
        op[256] = a4; op[320] = a5; op[384] = a6; op[448] = a7;
    }
}

// ---------------------------------------------------------------------------
// Split flash attention with k-outer / q-inner K/V reuse.
// Grid 512 = 16 bh x 4 qgroups x 8 splits (sp = bid&7 -> per-XCD K/V slice
// = 2MB if round-robin holds). Block: 80 queries (5x16) x 512 keys
// (4 tiles of 128). K/V staged ONCE per tile, reused by all 5 q-subtiles:
// L2 demand 311 MB -> ~85 MB.
// Phase 1 (subtile s): thread (qi1=t>>4, g=t&15) -> 8 logits, online softmax.
// Phase 3 (subtile s): wave owns 32-key slice; lane (qb,db): 4q x dims {db,db+16}.
// ---------------------------------------------------------------------------
#define KS_O   0        // Ks  [128][36] -> 4608
#define VST_O  4608     // VsT [32][132] -> 4224
#define PS_O   8832     // Ps  [16][132] -> 2112
#define QS_O   10944    // Qs  [80][36]  -> 2880
#define RX_O   13824    // Rx  [80][65]  -> 5200
#define RY_O   19024    // Ry  [80][10]  -> 800
#define MSK_O  19824    // 128
#define CF_O   19952    // 16
#define SM_TOT 19968    // 79,872 B -> 2 blocks/CU

__global__ __launch_bounds__(256, 2) void attn_split(
    const float* __restrict__ Q,    // [B][300][256] pre-scaled
    const float* __restrict__ K,    // [B][4096][256]
    const float* __restrict__ V,    // [B][4096][256]
    const float* __restrict__ RPX,  // [B*300][8][64]
    const float* __restrict__ RPY,  // [B*300][8][64]
    const float* __restrict__ mask, // [B][4096]
    float* __restrict__ part)
{
    __shared__ float sm[SM_TOT];

    const int bid = blockIdx.x;           // 0..511
    const int sp  = bid & 7;              // split (XCD if round-robin)
    const int r   = bid >> 3;             // 0..63
    const int bh  = r & 15;
    const int qg  = r >> 4;               // 0..3

    const int b  = bh >> 3, h = bh & 7;
    const int q0 = qg * QBLK;
    const int kbase = sp * KSPLIT;
    const int t  = threadIdx.x;
    const int wv = t >> 6, lane = t & 63;
    const int qi1 = t >> 4;               // phase 1: q row in subtile
    const int g   = t & 15;
    const int qb  = lane >> 4;            // phase 3
    const int db  = lane & 15;

    // ---- prologue: stage Q, Rx, Ry(8 local y rows) ----
    for (int i = t; i < QBLK * 8; i += 256) {
        int row = i >> 3, c = i & 7;
        int qr = q0 + row; if (qr >= NQT) qr = NQT - 1;
        *(float4*)&sm[QS_O + row * 36 + c * 4] =
            *(const float4*)(Q + ((size_t)(b * NQT + qr)) * 256 + h * HDIM + c * 4);
    }
    for (int i = t; i < QBLK * 64; i += 256) {
        int row = i >> 6, x = i & 63;
        int qr = q0 + row; if (qr >= NQT) qr = NQT - 1;
        sm[RX_O + row * 65 + x] = RPX[((size_t)(b * NQT + qr) * 8 + h) * 64 + x];
    }
    for (int i = t; i < QBLK * 8; i += 256) {
        int row = i >> 3, yy = i & 7;
        int qr = q0 + row; if (qr >= NQT) qr = NQT - 1;
        sm[RY_O + row * 10 + yy] = RPY[((size_t)(b * NQT + qr) * 8 + h) * 64 + sp * 8 + yy];
    }

    float m_r[NSUB], l_r[NSUB];
    float accq[NSUB][4][2];
    #pragma unroll
    for (int s = 0; s < NSUB; ++s) {
        m_r[s] = -1e30f; l_r[s] = 0.f;
        #pragma unroll
        for (int i = 0; i < 4; ++i) { accq[s][i][0] = 0.f; accq[s][i][1] = 0.f; }
    }

    for (int k0 = 0; k0 < KSPLIT; k0 += TK) {
        // stage K (row-major pad 36) + V^T (pad 132) + mask; prior reads are
        // protected by the trailing barrier of the previous subtile loop
        // (prologue writes are to disjoint regions).
        #pragma unroll
        for (int i = 0; i < 4; ++i) {
            int j = t + 256 * i;               // 0..1023
            int kk = j >> 3, seg = j & 7;
            size_t goff = ((size_t)(b * HWT + kbase + k0 + kk)) * 256 + h * HDIM + seg * 4;
            float4 kv = *(const float4*)(K + goff);
            float4 vv = *(const float4*)(V + goff);
            *(float4*)&sm[KS_O + kk * 36 + seg * 4] = kv;
            sm[VST_O + (seg * 4 + 0) * 132 + kk] = vv.x;
            sm[VST_O + (seg * 4 + 1) * 132 + kk] = vv.y;
            sm[VST_O + (seg * 4 + 2) * 132 + kk] = vv.z;
            sm[VST_O + (seg * 4 + 3) * 132 + kk] = vv.w;
        }
        if (t < TK) sm[MSK_O + t] = mask[(size_t)b * HWT + kbase + k0 + t];
        __syncthreads();

        #pragma unroll
        for (int s = 0; s < NSUB; ++s) {
            // ---- phase 1: logits + online softmax for subtile s ----
            const int qrl = s * 16 + qi1;      // local q row 0..79
            float4 qreg[8];
            #pragma unroll
            for (int c = 0; c < 8; ++c)
                qreg[c] = *(const float4*)&sm[QS_O + qrl * 36 + c * 4];

            float pb[8];
            float tmax = -1e30f;
            #pragma unroll
            for (int u = 0; u < 8; ++u) {
                const int kk = g + 16 * u;
                const float* kp = &sm[KS_O + kk * 36];
                float dot = 0.f;
                #pragma unroll
                for (int c = 0; c < 8; ++c) {
                    float4 kv = *(const float4*)(kp + c * 4);
                    dot = fmaf(qreg[c].x, kv.x, dot);
                    dot = fmaf(qreg[c].y, kv.y, dot);
                    dot = fmaf(qreg[c].z, kv.z, dot);
                    dot = fmaf(qreg[c].w, kv.w, dot);
                }
                const int xl = (kbase + k0 + kk) & 63;
                const int yl = (k0 + kk) >> 6;         // 0..7 local
                float sval = dot + sm[RX_O + qrl * 65 + xl]
                                 + sm[RY_O + qrl * 10 + yl]
                                 + sm[MSK_O + kk] * (-100.f);
                pb[u] = sval;
                tmax = fmaxf(tmax, sval);
            }
            #pragma unroll
            for (int off = 8; off; off >>= 1)
                tmax = fmaxf(tmax, __shfl_xor(tmax, off));
            const float mn = fmaxf(m_r[s], tmax);
            const float cf = __expf(m_r[s] - mn);
            float psum = 0.f;
            #pragma unroll
            for (int u = 0; u < 8; ++u) {
                float pv = __expf(pb[u] - mn);
                sm[PS_O + qi1 * 132 + g + 16 * u] = pv;
                psum += pv;
            }
            #pragma unroll
            for (int off = 8; off; off >>= 1)
                psum += __shfl_xor(psum, off);
            l_r[s] = l_r[s] * cf + psum;
            m_r[s] = mn;
            if (g == 0) sm[CF_O + qi1] = cf;
            __syncthreads();

            // ---- phase 3: PV for subtile s over this wave's 32-key slice ----
            float cfv[4];
            #pragma unroll
            for (int i = 0; i < 4; ++i) cfv[i] = sm[CF_O + qb * 4 + i];
            #pragma unroll
            for (int i = 0; i < 4; ++i) {
                accq[s][i][0] *= cfv[i];
                accq[s][i][1] *= cfv[i];
            }
            const int ks0 = wv * 32;
            #pragma unroll
            for (int kq = 0; kq < 32; kq += 4) {
                const int kk = ks0 + kq;
                float4 v0 = *(const float4*)&sm[VST_O + db * 132 + kk];
                float4 v1 = *(const float4*)&sm[VST_O + (db + 16) * 132 + kk];
                #pragma unroll
                for (int i = 0; i < 4; ++i) {
                    float4 pp = *(const float4*)&sm[PS_O + (qb * 4 + i) * 132 + kk];
                    accq[s][i][0] = fmaf(pp.x, v0.x, accq[s][i][0]);
                    accq[s][i][0] = fmaf(pp.y, v0.y, accq[s][i][0]);
                    accq[s][i][0] = fmaf(pp.z, v0.z, accq[s][i][0]);
                    accq[s][i][0] = fmaf(pp.w, v0.w, accq[s][i][0]);
                    accq[s][i][1] = fmaf(pp.x, v1.x, accq[s][i][1]);
                    accq[s][i][1] = fmaf(pp.y, v1.y, accq[s][i][1]);
                    accq[s][i][1] = fmaf(pp.z, v1.z, accq[s][i][1]);
                    accq[s][i][1] = fmaf(pp.w, v1.w, accq[s][i][1]);
                }
            }
            __syncthreads();   // protect Ps/Cf before next subtile overwrite
        }
    }

    // ---- epilogue: per subtile, write (m,l) and cross-wave-reduced acc ----
    // Alias reduce buffer [4][16*34] over the (dead) Ks region.
    #pragma unroll
    for (int s = 0; s < NSUB; ++s) {
        const size_t rec = (((size_t)bh * NQB20 + qg * NSUB + s) * NSPLIT + sp) * RECSZ;
        if (g == 0) {
            part[rec + qi1]      = m_r[s];
            part[rec + 16 + qi1] = l_r[s];
        }
        #pragma unroll
        for (int i = 0; i < 4; ++i) {
            sm[wv * 544 + (qb * 4 + i) * 34 + db]      = accq[s][i][0];
            sm[wv * 544 + (qb * 4 + i) * 34 + db + 16] = accq[s][i][1];
        }
        __syncthreads();
        {
            const int q16 = t >> 4, d2 = (t & 15) * 2;
            float r0 = 0.f, r1 = 0.f;
            #pragma unroll
            for (int w = 0; w < 4; ++w) {
                r0 += sm[w * 544 + q16 * 34 + d2];
                r1 += sm[w * 544 + q16 * 34 + d2 + 1];
            }
            *(float2*)&part[rec + 32 + q16 * 32 + d2] = make_float2(r0, r1);
        }
        __syncthreads();   // before next subtile reuses the alias buffer
    }
}

// ---------------------------------------------------------------------------
// Combine split partials (NSPLIT=8)
// ---------------------------------------------------------------------------
__global__ __launch_bounds__(256) void attn_combine(
    const float* __restrict__ part, float* __restrict__ Xout)
{
    const int gi  = blockIdx.x * 256 + threadIdx.x;   // 0..153599
    const int d   = gi & 31;
    const int row = gi >> 5;                          // 0..4799
    const int bh  = row / NQT;
    const int q   = row - bh * NQT;
    const int qblk = q >> 4, qi = q & 15;
    const float* rp = part + ((size_t)(bh * NQB20 + qblk) * NSPLIT) * RECSZ;

    float mv[NSPLIT], lv[NSPLIT];
    float M = -1e30f;
    #pragma unroll
    for (int s = 0; s < NSPLIT; ++s) {
        mv[s] = rp[s * RECSZ + qi];
        lv[s] = rp[s * RECSZ + 16 + qi];
        M = fmaxf(M, mv[s]);
    }
    float num = 0.f, den = 0.f;
    #pragma unroll
    for (int s = 0; s < NSPLIT; ++s) {
        float w = __expf(mv[s] - M);
        den = fmaf(w, lv[s], den);
        num = fmaf(w, rp[s * RECSZ + 32 + qi * 32 + d], num);
    }
    const int b = bh >> 3, h = bh & 7;
    Xout[((size_t)(b * NQT + q)) * 256 + h * HDIM + d] = num / den;
}

// ---------------------------------------------------------------------------
extern "C" void kernel_launch(void* const* d_in, const int* in_sizes, int n_in,
                              void* d_out, int out_size, void* d_ws, size_t ws_size,
                              hipStream_t stream)
{
    (void)in_sizes; (void)n_in; (void)out_size; (void)ws_size;

    const float* raw_query = (const float*)d_in[0];
    const float* query_pos = (const float*)d_in[1];
    const float* refpts    = (const float*)d_in[2];
    const float* raw_src   = (const float*)d_in[3];
    const float* src_pos   = (const float*)d_in[4];
    const float* mask      = (const float*)d_in[5];
    const float* Wq = (const float*)d_in[7];
    const float* bq = (const float*)d_in[8];
    const float* Wk = (const float*)d_in[9];
    const float* bk = (const float*)d_in[10];
    const float* Wv = (const float*)d_in[11];
    const float* bv = (const float*)d_in[12];
    const float* Wp = (const float*)d_in[13];
    const float* bp = (const float*)d_in[14];
    const float* c1w1 = (const float*)d_in[15];
    const float* c1b1 = (const float*)d_in[16];
    const float* c1w2 = (const float*)d_in[17];
    const float* c2w1 = (const float*)d_in[18];
    const float* c2b1 = (const float*)d_in[19];
    const float* c2w2 = (const float*)d_in[20];

    float* ws = (float*)d_ws;
    float* Qf   = ws;                   // 153600
    float* Kf   = Qf + 153600;          // 2097152
    float* Vf   = Kf + 2097152;         // 2097152
    float* RX   = Vf + 2097152;         // 307200
    float* RY   = RX + 307200;          // 307200
    float* Xf   = RY + 307200;          // 153600
    float* PART = Xf + 153600;          // 16*20*8*544 = 1392640

    dim3 blk(256);
    const float qscale = 0.17677669529663687f;  // 32^-0.5

    proj_small<<<dim3(19, 4), blk, 0, stream>>>(raw_query, query_pos, Wq, bq, Qf, 600, qscale);
    proj_kv<<<dim3(512), blk, 0, stream>>>(raw_src, src_pos, Wk, bk, Wv, bv, Kf, Vf);
    rpe_kernel<<<dim3(300, 2), blk, 0, stream>>>(refpts, c1w1, c1b1, c1w2, c2w1, c2b1, c2w2, RX, RY);
    attn_split<<<dim3(512), blk, 0, stream>>>(Qf, Kf, Vf, RX, RY, mask, PART);
    attn_combine<<<dim3(600), blk, 0, stream>>>(PART, Xf);
    proj_small<<<dim3(19, 4), blk, 0, stream>>>(Xf, nullptr, Wp, bp, (float*)d_out, 600, 1.f);
}

// Round 9
// 1085.826 us; speedup vs baseline: 1.0335x; 1.0335x over previous
//
#include <hip/hip_runtime.h>

#define NQT   300
#define HWT   4096
#define NHEAD 8
#define HDIM  32
#define QT     16
#define NSUB   5          // 5 sub-tiles of 16 q = 80 q per block
#define QBLK   80
#define TK     128
#define NSPLIT 8
#define KSPLIT 512
#define NQB20  20         // 16-q record blocks allocated (19 valid + 1 pad)
#define RECSZ  544        // 16 m + 16 l + 16*32 acc

// ---------------------------------------------------------------------------
// Fused K+V projection (unchanged)
// ---------------------------------------------------------------------------
__global__ __launch_bounds__(256, 2) void proj_kv(
    const float* __restrict__ src, const float* __restrict__ pos,
    const float* __restrict__ Wk, const float* __restrict__ bk,
    const float* __restrict__ Wv, const float* __restrict__ bv,
    float* __restrict__ Kout, float* __restrict__ Vout)
{
    __shared__ float As[16][132];   // [k][row]
    const int bid  = blockIdx.x;          // 0..511
    const int xcd  = bid & 7;
    const int idx  = bid >> 3;            // 0..63
    const int mblk = xcd * 8 + (idx >> 3);
    const int sub  = idx & 7;
    const int isV  = sub >> 2;
    const int n0   = (sub & 3) * 64;
    const int m0   = mblk * 128;

    const float* W    = isV ? Wv : Wk;
    const float* bias = isV ? bv : bk;
    float* Out        = isV ? Vout : Kout;

    const int t  = threadIdx.x;
    const int rg = t >> 4, cg = t & 15;
    const int ar = t >> 2, ac4 = t & 3;

    float acc[8][4] = {};

    for (int k0 = 0; k0 < 256; k0 += 16) {
        float4 av[2];
        #pragma unroll
        for (int i = 0; i < 2; ++i) {
            const int row = m0 + ar + 64 * i;
            av[i] = *(const float4*)(src + (size_t)row * 256 + k0 + ac4 * 4);
            if (!isV) {
                float4 pv = *(const float4*)(pos + (size_t)row * 256 + k0 + ac4 * 4);
                av[i].x += pv.x; av[i].y += pv.y; av[i].z += pv.z; av[i].w += pv.w;
            }
        }
        __syncthreads();
        #pragma unroll
        for (int i = 0; i < 2; ++i) {
            const int row = ar + 64 * i;
            As[ac4 * 4 + 0][row] = av[i].x;
            As[ac4 * 4 + 1][row] = av[i].y;
            As[ac4 * 4 + 2][row] = av[i].z;
            As[ac4 * 4 + 3][row] = av[i].w;
        }
        __syncthreads();

        float4 bcur = *(const float4*)(W + (size_t)k0 * 256 + n0 + cg * 4);
        #pragma unroll
        for (int k = 0; k < 16; ++k) {
            float4 bnext;
            if (k < 15)
                bnext = *(const float4*)(W + (size_t)(k0 + k + 1) * 256 + n0 + cg * 4);
            float4 a0 = *(const float4*)&As[k][rg * 8];
            float4 a1 = *(const float4*)&As[k][rg * 8 + 4];
            float a[8] = {a0.x, a0.y, a0.z, a0.w, a1.x, a1.y, a1.z, a1.w};
            float bb[4] = {bcur.x, bcur.y, bcur.z, bcur.w};
            #pragma unroll
            for (int i = 0; i < 8; ++i)
                #pragma unroll
                for (int j = 0; j < 4; ++j)
                    acc[i][j] = fmaf(a[i], bb[j], acc[i][j]);
            if (k < 15) bcur = bnext;
        }
    }

    float4 bb = *(const float4*)(bias + n0 + cg * 4);
    #pragma unroll
    for (int i = 0; i < 8; ++i) {
        const int gr = m0 + rg * 8 + i;
        float4 o;
        o.x = acc[i][0] + bb.x;
        o.y = acc[i][1] + bb.y;
        o.z = acc[i][2] + bb.z;
        o.w = acc[i][3] + bb.w;
        *(float4*)(Out + (size_t)gr * 256 + n0 + cg * 4) = o;
    }
}

// ---------------------------------------------------------------------------
// Small projection (M=600) — unchanged
// ---------------------------------------------------------------------------
__global__ __launch_bounds__(256) void proj_small(
    const float* __restrict__ X, const float* __restrict__ Xpos,
    const float* __restrict__ W, const float* __restrict__ bias,
    float* __restrict__ Out, int M, float scale)
{
    __shared__ float As[16][36];
    const int m0 = blockIdx.x * 32;
    const int n0 = blockIdx.y * 64;
    const int t  = threadIdx.x;
    const int rg = t >> 4, cg = t & 15;

    float acc[2][4] = {};

    for (int k0 = 0; k0 < 256; k0 += 16) {
        float4 av = make_float4(0.f, 0.f, 0.f, 0.f);
        const int ar = t >> 2, ac4 = t & 3;
        if (t < 128) {
            int row = m0 + ar;
            if (row < M) {
                av = *(const float4*)(X + (size_t)row * 256 + k0 + ac4 * 4);
                if (Xpos) {
                    float4 pv = *(const float4*)(Xpos + (size_t)row * 256 + k0 + ac4 * 4);
                    av.x += pv.x; av.y += pv.y; av.z += pv.z; av.w += pv.w;
                }
            }
        }
        __syncthreads();
        if (t < 128) {
            As[ac4 * 4 + 0][ar] = av.x;
            As[ac4 * 4 + 1][ar] = av.y;
            As[ac4 * 4 + 2][ar] = av.z;
            As[ac4 * 4 + 3][ar] = av.w;
        }
        __syncthreads();

        float4 bcur = *(const float4*)(W + (size_t)k0 * 256 + n0 + cg * 4);
        #pragma unroll
        for (int k = 0; k < 16; ++k) {
            float4 bnext;
            if (k < 15)
                bnext = *(const float4*)(W + (size_t)(k0 + k + 1) * 256 + n0 + cg * 4);
            float a0 = As[k][rg * 2], a1 = As[k][rg * 2 + 1];
            acc[0][0] = fmaf(a0, bcur.x, acc[0][0]);
            acc[0][1] = fmaf(a0, bcur.y, acc[0][1]);
            acc[0][2] = fmaf(a0, bcur.z, acc[0][2]);
            acc[0][3] = fmaf(a0, bcur.w, acc[0][3]);
            acc[1][0] = fmaf(a1, bcur.x, acc[1][0]);
            acc[1][1] = fmaf(a1, bcur.y, acc[1][1]);
            acc[1][2] = fmaf(a1, bcur.z, acc[1][2]);
            acc[1][3] = fmaf(a1, bcur.w, acc[1][3]);
            if (k < 15) bcur = bnext;
        }
    }

    float4 bb = *(const float4*)(bias + n0 + cg * 4);
    #pragma unroll
    for (int i = 0; i < 2; ++i) {
        const int gr = m0 + rg * 2 + i;
        if (gr < M) {
            float4 o;
            o.x = (acc[i][0] + bb.x) * scale;
            o.y = (acc[i][1] + bb.y) * scale;
            o.z = (acc[i][2] + bb.z) * scale;
            o.w = (acc[i][3] + bb.w) * scale;
            *(float4*)(Out + (size_t)gr * 256 + n0 + cg * 4) = o;
        }
    }
}

// ---------------------------------------------------------------------------
// RPE tables — unchanged
// ---------------------------------------------------------------------------
__global__ __launch_bounds__(256) void rpe_kernel(
    const float* __restrict__ refpts,
    const float* __restrict__ w1x, const float* __restrict__ b1x, const float* __restrict__ w2x,
    const float* __restrict__ w1y, const float* __restrict__ b1y, const float* __restrict__ w2y,
    float* __restrict__ outx, float* __restrict__ outy)
{
    const int axis = blockIdx.y;
    const int t    = threadIdx.x;
    const int item = blockIdx.x * 128 + (t >> 1);
    const int half = t & 1;
    const int bq   = __builtin_amdgcn_readfirstlane(item >> 6);
    const int pos  = item & 63;

    const float* w1 = axis ? w1y : w1x;
    const float* b1 = axis ? b1y : b1x;
    const float* w2 = axis ? w2y : w2x;

    float4 r = *(const float4*)(refpts + (size_t)bq * 4);
    float ctr  = axis ? r.y : r.x;
    float hlf  = (axis ? r.w : r.z) * 0.5f;
    float lo = (ctr - hlf) * 1024.f;
    float hi = (ctr + hlf) * 1024.f;
    float p  = ((float)pos + 0.5f) * 16.f;
    float d0 = lo - p, d1 = hi - p;

    float a0 = 0.f, a1 = 0.f, a2 = 0.f, a3 = 0.f;
    float a4 = 0.f, a5 = 0.f, a6 = 0.f, a7 = 0.f;

    const int h0 = half * 256;
    #pragma unroll 4
    for (int i = 0; i < 256; ++i) {
        const int hid = h0 + i;
        float hv = fmaf(d0, w1[hid], fmaf(d1, w1[512 + hid], b1[hid]));
        hv = fmaxf(hv, 0.f);
        float4 wA = *(const float4*)(w2 + (size_t)hid * 8);
        float4 wB = *(const float4*)(w2 + (size_t)hid * 8 + 4);
        a0 = fmaf(hv, wA.x, a0); a1 = fmaf(hv, wA.y, a1);
        a2 = fmaf(hv, wA.z, a2); a3 = fmaf(hv, wA.w, a3);
        a4 = fmaf(hv, wB.x, a4); a5 = fmaf(hv, wB.y, a5);
        a6 = fmaf(hv, wB.z, a6); a7 = fmaf(hv, wB.w, a7);
    }
    a0 += __shfl_xor(a0, 1); a1 += __shfl_xor(a1, 1);
    a2 += __shfl_xor(a2, 1); a3 += __shfl_xor(a3, 1);
    a4 += __shfl_xor(a4, 1); a5 += __shfl_xor(a5, 1);
    a6 += __shfl_xor(a6, 1); a7 += __shfl_xor(a7, 1);

    if (half == 0) {
        float* op = (axis ? outy : outx) + (size_t)bq * 512 + pos;
        op[0]   = a0; op[64]  = a1; op[128] = a2; op[192] = a3;
        op[256] = a4; op[320] = a5; op[384] = a6; op[448] = a7;
    }
}

// ---------------------------------------------------------------------------
// Split flash attention, k-outer / q-inner K/V reuse (round-8 structure)
// with the NSUB loop FORCE-UNROLLED via macros so every accumulator index is
// compile-time constant (round-8 left `s` runtime -> accq spilled to scratch:
// WRITE_SIZE 1.34 GB, 818 us. Rule: static indices or scratch).
// ---------------------------------------------------------------------------
#define KS_O   0        // Ks  [128][36] -> 4608
#define VST_O  4608     // VsT [32][132] -> 4224
#define PS_O   8832     // Ps  [16][132] -> 2112
#define QS_O   10944    // Qs  [80][36]  -> 2880
#define RX_O   13824    // Rx  [80][65]  -> 5200
#define RY_O   19024    // Ry  [80][10]  -> 800
#define MSK_O  19824    // 128
#define CF_O   19952    // 16
#define SM_TOT 19968    // 79,872 B -> 2 blocks/CU

// Phase 1 + phase 3 for one 16-query subtile S (compile-time constant).
#define DO_SUBTILE(S, ACC, MR, LR)                                            \
    {                                                                         \
        const int qrl = (S) * 16 + qi1;                                       \
        float4 qreg[8];                                                       \
        _Pragma("unroll")                                                     \
        for (int c = 0; c < 8; ++c)                                           \
            qreg[c] = *(const float4*)&sm[QS_O + qrl * 36 + c * 4];           \
        float pb[8];                                                          \
        float tmax = -1e30f;                                                  \
        _Pragma("unroll")                                                     \
        for (int u = 0; u < 8; ++u) {                                         \
            const int kk = g + 16 * u;                                        \
            const float* kp = &sm[KS_O + kk * 36];                            \
            float dot = 0.f;                                                  \
            _Pragma("unroll")                                                 \
            for (int c = 0; c < 8; ++c) {                                     \
                float4 kv = *(const float4*)(kp + c * 4);                     \
                dot = fmaf(qreg[c].x, kv.x, dot);                             \
                dot = fmaf(qreg[c].y, kv.y, dot);                             \
                dot = fmaf(qreg[c].z, kv.z, dot);                             \
                dot = fmaf(qreg[c].w, kv.w, dot);                             \
            }                                                                 \
            const int xl = (kbase + k0 + kk) & 63;                            \
            const int yl = (k0 + kk) >> 6;                                    \
            float sval = dot + sm[RX_O + qrl * 65 + xl]                       \
                             + sm[RY_O + qrl * 10 + yl]                       \
                             + sm[MSK_O + kk] * (-100.f);                     \
            pb[u] = sval;                                                     \
            tmax = fmaxf(tmax, sval);                                         \
        }                                                                     \
        _Pragma("unroll")                                                     \
        for (int off = 8; off; off >>= 1)                                     \
            tmax = fmaxf(tmax, __shfl_xor(tmax, off));                        \
        const float mn = fmaxf((MR), tmax);                                   \
        const float cfe = __expf((MR) - mn);                                  \
        float psum = 0.f;                                                     \
        _Pragma("unroll")                                                     \
        for (int u = 0; u < 8; ++u) {                                         \
            float pv = __expf(pb[u] - mn);                                    \
            sm[PS_O + qi1 * 132 + g + 16 * u] = pv;                           \
            psum += pv;                                                       \
        }                                                                     \
        _Pragma("unroll")                                                     \
        for (int off = 8; off; off >>= 1)                                     \
            psum += __shfl_xor(psum, off);                                    \
        (LR) = (LR) * cfe + psum;                                             \
        (MR) = mn;                                                            \
        if (g == 0) sm[CF_O + qi1] = cfe;                                     \
        __syncthreads();                                                      \
        float cfv0 = sm[CF_O + qb * 4 + 0];                                   \
        float cfv1 = sm[CF_O + qb * 4 + 1];                                   \
        float cfv2 = sm[CF_O + qb * 4 + 2];                                   \
        float cfv3 = sm[CF_O + qb * 4 + 3];                                   \
        ACC[0][0] *= cfv0; ACC[0][1] *= cfv0;                                 \
        ACC[1][0] *= cfv1; ACC[1][1] *= cfv1;                                 \
        ACC[2][0] *= cfv2; ACC[2][1] *= cfv2;                                 \
        ACC[3][0] *= cfv3; ACC[3][1] *= cfv3;                                 \
        const int ks0 = wv * 32;                                              \
        _Pragma("unroll")                                                     \
        for (int kq = 0; kq < 32; kq += 4) {                                  \
            const int kk = ks0 + kq;                                          \
            float4 v0 = *(const float4*)&sm[VST_O + db * 132 + kk];           \
            float4 v1 = *(const float4*)&sm[VST_O + (db + 16) * 132 + kk];    \
            _Pragma("unroll")                                                 \
            for (int i = 0; i < 4; ++i) {                                     \
                float4 pp = *(const float4*)&sm[PS_O + (qb * 4 + i) * 132 + kk]; \
                ACC[i][0] = fmaf(pp.x, v0.x, ACC[i][0]);                      \
                ACC[i][0] = fmaf(pp.y, v0.y, ACC[i][0]);                      \
                ACC[i][0] = fmaf(pp.z, v0.z, ACC[i][0]);                      \
                ACC[i][0] = fmaf(pp.w, v0.w, ACC[i][0]);                      \
                ACC[i][1] = fmaf(pp.x, v1.x, ACC[i][1]);                      \
                ACC[i][1] = fmaf(pp.y, v1.y, ACC[i][1]);                      \
                ACC[i][1] = fmaf(pp.z, v1.z, ACC[i][1]);                      \
                ACC[i][1] = fmaf(pp.w, v1.w, ACC[i][1]);                      \
            }                                                                 \
        }                                                                     \
        __syncthreads();                                                      \
    }

// Epilogue for one subtile: write (m,l), LDS cross-wave reduce, write acc.
#define EPI_SUBTILE(S, ACC, MR, LR)                                           \
    {                                                                         \
        const size_t rec =                                                    \
            (((size_t)bh * NQB20 + qg * NSUB + (S)) * NSPLIT + sp) * RECSZ;   \
        if (g == 0) {                                                         \
            part[rec + qi1]      = (MR);                                      \
            part[rec + 16 + qi1] = (LR);                                      \
        }                                                                     \
        _Pragma("unroll")                                                     \
        for (int i = 0; i < 4; ++i) {                                         \
            sm[wv * 544 + (qb * 4 + i) * 34 + db]      = ACC[i][0];           \
            sm[wv * 544 + (qb * 4 + i) * 34 + db + 16] = ACC[i][1];           \
        }                                                                     \
        __syncthreads();                                                      \
        {                                                                     \
            const int q16 = t >> 4, d2 = (t & 15) * 2;                        \
            float r0 = 0.f, r1 = 0.f;                                         \
            _Pragma("unroll")                                                 \
            for (int w = 0; w < 4; ++w) {                                     \
                r0 += sm[w * 544 + q16 * 34 + d2];                            \
                r1 += sm[w * 544 + q16 * 34 + d2 + 1];                        \
            }                                                                 \
            *(float2*)&part[rec + 32 + q16 * 32 + d2] = make_float2(r0, r1);  \
        }                                                                     \
        __syncthreads();                                                      \
    }

__global__ __launch_bounds__(256, 2) void attn_split(
    const float* __restrict__ Q,    // [B][300][256] pre-scaled
    const float* __restrict__ K,    // [B][4096][256]
    const float* __restrict__ V,    // [B][4096][256]
    const float* __restrict__ RPX,  // [B*300][8][64]
    const float* __restrict__ RPY,  // [B*300][8][64]
    const float* __restrict__ mask, // [B][4096]
    float* __restrict__ part)
{
    __shared__ float sm[SM_TOT];

    const int bid = blockIdx.x;           // 0..511
    const int sp  = bid & 7;              // split (XCD if round-robin)
    const int r   = bid >> 3;             // 0..63
    const int bh  = r & 15;
    const int qg  = r >> 4;               // 0..3

    const int b  = bh >> 3, h = bh & 7;
    const int q0 = qg * QBLK;
    const int kbase = sp * KSPLIT;
    const int t  = threadIdx.x;
    const int wv = t >> 6, lane = t & 63;
    const int qi1 = t >> 4;               // phase 1: q row in subtile
    const int g   = t & 15;
    const int qb  = lane >> 4;            // phase 3
    const int db  = lane & 15;

    // ---- prologue: stage Q, Rx, Ry(8 local y rows) ----
    for (int i = t; i < QBLK * 8; i += 256) {
        int row = i >> 3, c = i & 7;
        int qr = q0 + row; if (qr >= NQT) qr = NQT - 1;
        *(float4*)&sm[QS_O + row * 36 + c * 4] =
            *(const float4*)(Q + ((size_t)(b * NQT + qr)) * 256 + h * HDIM + c * 4);
    }
    for (int i = t; i < QBLK * 64; i += 256) {
        int row = i >> 6, x = i & 63;
        int qr = q0 + row; if (qr >= NQT) qr = NQT - 1;
        sm[RX_O + row * 65 + x] = RPX[((size_t)(b * NQT + qr) * 8 + h) * 64 + x];
    }
    for (int i = t; i < QBLK * 8; i += 256) {
        int row = i >> 3, yy = i & 7;
        int qr = q0 + row; if (qr >= NQT) qr = NQT - 1;
        sm[RY_O + row * 10 + yy] = RPY[((size_t)(b * NQT + qr) * 8 + h) * 64 + sp * 8 + yy];
    }

    float m_0 = -1e30f, m_1 = -1e30f, m_2 = -1e30f, m_3 = -1e30f, m_4 = -1e30f;
    float l_0 = 0.f, l_1 = 0.f, l_2 = 0.f, l_3 = 0.f, l_4 = 0.f;
    float acc0[4][2] = {}, acc1[4][2] = {}, acc2[4][2] = {};
    float acc3[4][2] = {}, acc4[4][2] = {};

    for (int k0 = 0; k0 < KSPLIT; k0 += TK) {
        // stage K (row-major pad 36) + V^T (pad 132) + mask
        #pragma unroll
        for (int i = 0; i < 4; ++i) {
            int j = t + 256 * i;               // 0..1023
            int kk = j >> 3, seg = j & 7;
            size_t goff = ((size_t)(b * HWT + kbase + k0 + kk)) * 256 + h * HDIM + seg * 4;
            float4 kv = *(const float4*)(K + goff);
            float4 vv = *(const float4*)(V + goff);
            *(float4*)&sm[KS_O + kk * 36 + seg * 4] = kv;
            sm[VST_O + (seg * 4 + 0) * 132 + kk] = vv.x;
            sm[VST_O + (seg * 4 + 1) * 132 + kk] = vv.y;
            sm[VST_O + (seg * 4 + 2) * 132 + kk] = vv.z;
            sm[VST_O + (seg * 4 + 3) * 132 + kk] = vv.w;
        }
        if (t < TK) sm[MSK_O + t] = mask[(size_t)b * HWT + kbase + k0 + t];
        __syncthreads();

        DO_SUBTILE(0, acc0, m_0, l_0);
        DO_SUBTILE(1, acc1, m_1, l_1);
        DO_SUBTILE(2, acc2, m_2, l_2);
        DO_SUBTILE(3, acc3, m_3, l_3);
        DO_SUBTILE(4, acc4, m_4, l_4);
    }

    EPI_SUBTILE(0, acc0, m_0, l_0);
    EPI_SUBTILE(1, acc1, m_1, l_1);
    EPI_SUBTILE(2, acc2, m_2, l_2);
    EPI_SUBTILE(3, acc3, m_3, l_3);
    EPI_SUBTILE(4, acc4, m_4, l_4);
}

// ---------------------------------------------------------------------------
// Combine split partials (NSPLIT=8)
// ---------------------------------------------------------------------------
__global__ __launch_bounds__(256) void attn_combine(
    const float* __restrict__ part, float* __restrict__ Xout)
{
    const int gi  = blockIdx.x * 256 + threadIdx.x;   // 0..153599
    const int d   = gi & 31;
    const int row = gi >> 5;                          // 0..4799
    const int bh  = row / NQT;
    const int q   = row - bh * NQT;
    const int qblk = q >> 4, qi = q & 15;
    const float* rp = part + ((size_t)(bh * NQB20 + qblk) * NSPLIT) * RECSZ;

    float mv[NSPLIT], lv[NSPLIT];
    float M = -1e30f;
    #pragma unroll
    for (int s = 0; s < NSPLIT; ++s) {
        mv[s] = rp[s * RECSZ + qi];
        lv[s] = rp[s * RECSZ + 16 + qi];
        M = fmaxf(M, mv[s]);
    }
    float num = 0.f, den = 0.f;
    #pragma unroll
    for (int s = 0; s < NSPLIT; ++s) {
        float w = __expf(mv[s] - M);
        den = fmaf(w, lv[s], den);
        num = fmaf(w, rp[s * RECSZ + 32 + qi * 32 + d], num);
    }
    const int b = bh >> 3, h = bh & 7;
    Xout[((size_t)(b * NQT + q)) * 256 + h * HDIM + d] = num / den;
}

// ---------------------------------------------------------------------------
extern "C" void kernel_launch(void* const* d_in, const int* in_sizes, int n_in,
                              void* d_out, int out_size, void* d_ws, size_t ws_size,
                              hipStream_t stream)
{
    (void)in_sizes; (void)n_in; (void)out_size; (void)ws_size;

    const float* raw_query = (const float*)d_in[0];
    const float* query_pos = (const float*)d_in[1];
    const float* refpts    = (const float*)d_in[2];
    const float* raw_src   = (const float*)d_in[3];
    const float* src_pos   = (const float*)d_in[4];
    const float* mask      = (const float*)d_in[5];
    const float* Wq = (const float*)d_in[7];
    const float* bq = (const float*)d_in[8];
    const float* Wk = (const float*)d_in[9];
    const float* bk = (const float*)d_in[10];
    const float* Wv = (const float*)d_in[11];
    const float* bv = (const float*)d_in[12];
    const float* Wp = (const float*)d_in[13];
    const float* bp = (const float*)d_in[14];
    const float* c1w1 = (const float*)d_in[15];
    const float* c1b1 = (const float*)d_in[16];
    const float* c1w2 = (const float*)d_in[17];
    const float* c2w1 = (const float*)d_in[18];
    const float* c2b1 = (const float*)d_in[19];
    const float* c2w2 = (const float*)d_in[20];

    float* ws = (float*)d_ws;
    float* Qf   = ws;                   // 153600
    float* Kf   = Qf + 153600;          // 2097152
    float* Vf   = Kf + 2097152;         // 2097152
    float* RX   = Vf + 2097152;         // 307200
    float* RY   = RX + 307200;          // 307200
    float* Xf   = RY + 307200;          // 153600
    float* PART = Xf + 153600;          // 16*20*8*544 = 1392640

    dim3 blk(256);
    const float qscale = 0.17677669529663687f;  // 32^-0.5

    proj_small<<<dim3(19, 4), blk, 0, stream>>>(raw_query, query_pos, Wq, bq, Qf, 600, qscale);
    proj_kv<<<dim3(512), blk, 0, stream>>>(raw_src, src_pos, Wk, bk, Wv, bv, Kf, Vf);
    rpe_kernel<<<dim3(300, 2), blk, 0, stream>>>(refpts, c1w1, c1b1, c1w2, c2w1, c2b1, c2w2, RX, RY);
    attn_split<<<dim3(512), blk, 0, stream>>>(Qf, Kf, Vf, RX, RY, mask, PART);
    attn_combine<<<dim3(600), blk, 0, stream>>>(PART, Xf);
    proj_small<<<dim3(19, 4), blk, 0, stream>>>(Xf, nullptr, Wp, bp, (float*)d_out, 600, 1.f);
}

// Round 10
// 482.601 us; speedup vs baseline: 2.3252x; 2.2499x over previous
//
#include <hip/hip_runtime.h>

#define NQT   300
#define HWT   4096
#define NHEAD 8
#define HDIM  32
#define TK    128
#define QB8   8          // queries per block
#define NQB8  38         // ceil(300/8)

// ---------------------------------------------------------------------------
// Fused K+V projection (unchanged since r2; never yet profiled — isolate)
// ---------------------------------------------------------------------------
__global__ __launch_bounds__(256, 2) void proj_kv(
    const float* __restrict__ src, const float* __restrict__ pos,
    const float* __restrict__ Wk, const float* __restrict__ bk,
    const float* __restrict__ Wv, const float* __restrict__ bv,
    float* __restrict__ Kout, float* __restrict__ Vout)
{
    __shared__ float As[16][132];   // [k][row]
    const int bid  = blockIdx.x;          // 0..511
    const int xcd  = bid & 7;
    const int idx  = bid >> 3;            // 0..63
    const int mblk = xcd * 8 + (idx >> 3);
    const int sub  = idx & 7;
    const int isV  = sub >> 2;
    const int n0   = (sub & 3) * 64;
    const int m0   = mblk * 128;

    const float* W    = isV ? Wv : Wk;
    const float* bias = isV ? bv : bk;
    float* Out        = isV ? Vout : Kout;

    const int t  = threadIdx.x;
    const int rg = t >> 4, cg = t & 15;
    const int ar = t >> 2, ac4 = t & 3;

    float acc[8][4] = {};

    for (int k0 = 0; k0 < 256; k0 += 16) {
        float4 av[2];
        #pragma unroll
        for (int i = 0; i < 2; ++i) {
            const int row = m0 + ar + 64 * i;
            av[i] = *(const float4*)(src + (size_t)row * 256 + k0 + ac4 * 4);
            if (!isV) {
                float4 pv = *(const float4*)(pos + (size_t)row * 256 + k0 + ac4 * 4);
                av[i].x += pv.x; av[i].y += pv.y; av[i].z += pv.z; av[i].w += pv.w;
            }
        }
        __syncthreads();
        #pragma unroll
        for (int i = 0; i < 2; ++i) {
            const int row = ar + 64 * i;
            As[ac4 * 4 + 0][row] = av[i].x;
            As[ac4 * 4 + 1][row] = av[i].y;
            As[ac4 * 4 + 2][row] = av[i].z;
            As[ac4 * 4 + 3][row] = av[i].w;
        }
        __syncthreads();

        float4 bcur = *(const float4*)(W + (size_t)k0 * 256 + n0 + cg * 4);
        #pragma unroll
        for (int k = 0; k < 16; ++k) {
            float4 bnext;
            if (k < 15)
                bnext = *(const float4*)(W + (size_t)(k0 + k + 1) * 256 + n0 + cg * 4);
            float4 a0 = *(const float4*)&As[k][rg * 8];
            float4 a1 = *(const float4*)&As[k][rg * 8 + 4];
            float a[8] = {a0.x, a0.y, a0.z, a0.w, a1.x, a1.y, a1.z, a1.w};
            float bb[4] = {bcur.x, bcur.y, bcur.z, bcur.w};
            #pragma unroll
            for (int i = 0; i < 8; ++i)
                #pragma unroll
                for (int j = 0; j < 4; ++j)
                    acc[i][j] = fmaf(a[i], bb[j], acc[i][j]);
            if (k < 15) bcur = bnext;
        }
    }

    float4 bb = *(const float4*)(bias + n0 + cg * 4);
    #pragma unroll
    for (int i = 0; i < 8; ++i) {
        const int gr = m0 + rg * 8 + i;
        float4 o;
        o.x = acc[i][0] + bb.x;
        o.y = acc[i][1] + bb.y;
        o.z = acc[i][2] + bb.z;
        o.w = acc[i][3] + bb.w;
        *(float4*)(Out + (size_t)gr * 256 + n0 + cg * 4) = o;
    }
}

// ---------------------------------------------------------------------------
// Small projection (M=600) — unchanged
// ---------------------------------------------------------------------------
__global__ __launch_bounds__(256) void proj_small(
    const float* __restrict__ X, const float* __restrict__ Xpos,
    const float* __restrict__ W, const float* __restrict__ bias,
    float* __restrict__ Out, int M, float scale)
{
    __shared__ float As[16][36];
    const int m0 = blockIdx.x * 32;
    const int n0 = blockIdx.y * 64;
    const int t  = threadIdx.x;
    const int rg = t >> 4, cg = t & 15;

    float acc[2][4] = {};

    for (int k0 = 0; k0 < 256; k0 += 16) {
        float4 av = make_float4(0.f, 0.f, 0.f, 0.f);
        const int ar = t >> 2, ac4 = t & 3;
        if (t < 128) {
            int row = m0 + ar;
            if (row < M) {
                av = *(const float4*)(X + (size_t)row * 256 + k0 + ac4 * 4);
                if (Xpos) {
                    float4 pv = *(const float4*)(Xpos + (size_t)row * 256 + k0 + ac4 * 4);
                    av.x += pv.x; av.y += pv.y; av.z += pv.z; av.w += pv.w;
                }
            }
        }
        __syncthreads();
        if (t < 128) {
            As[ac4 * 4 + 0][ar] = av.x;
            As[ac4 * 4 + 1][ar] = av.y;
            As[ac4 * 4 + 2][ar] = av.z;
            As[ac4 * 4 + 3][ar] = av.w;
        }
        __syncthreads();

        float4 bcur = *(const float4*)(W + (size_t)k0 * 256 + n0 + cg * 4);
        #pragma unroll
        for (int k = 0; k < 16; ++k) {
            float4 bnext;
            if (k < 15)
                bnext = *(const float4*)(W + (size_t)(k0 + k + 1) * 256 + n0 + cg * 4);
            float a0 = As[k][rg * 2], a1 = As[k][rg * 2 + 1];
            acc[0][0] = fmaf(a0, bcur.x, acc[0][0]);
            acc[0][1] = fmaf(a0, bcur.y, acc[0][1]);
            acc[0][2] = fmaf(a0, bcur.z, acc[0][2]);
            acc[0][3] = fmaf(a0, bcur.w, acc[0][3]);
            acc[1][0] = fmaf(a1, bcur.x, acc[1][0]);
            acc[1][1] = fmaf(a1, bcur.y, acc[1][1]);
            acc[1][2] = fmaf(a1, bcur.z, acc[1][2]);
            acc[1][3] = fmaf(a1, bcur.w, acc[1][3]);
            if (k < 15) bcur = bnext;
        }
    }

    float4 bb = *(const float4*)(bias + n0 + cg * 4);
    #pragma unroll
    for (int i = 0; i < 2; ++i) {
        const int gr = m0 + rg * 2 + i;
        if (gr < M) {
            float4 o;
            o.x = (acc[i][0] + bb.x) * scale;
            o.y = (acc[i][1] + bb.y) * scale;
            o.z = (acc[i][2] + bb.z) * scale;
            o.w = (acc[i][3] + bb.w) * scale;
            *(float4*)(Out + (size_t)gr * 256 + n0 + cg * 4) = o;
        }
    }
}

// ---------------------------------------------------------------------------
// RPE tables — unchanged
// ---------------------------------------------------------------------------
__global__ __launch_bounds__(256) void rpe_kernel(
    const float* __restrict__ refpts,
    const float* __restrict__ w1x, const float* __restrict__ b1x, const float* __restrict__ w2x,
    const float* __restrict__ w1y, const float* __restrict__ b1y, const float* __restrict__ w2y,
    float* __restrict__ outx, float* __restrict__ outy)
{
    const int axis = blockIdx.y;
    const int t    = threadIdx.x;
    const int item = blockIdx.x * 128 + (t >> 1);
    const int half = t & 1;
    const int bq   = __builtin_amdgcn_readfirstlane(item >> 6);
    const int pos  = item & 63;

    const float* w1 = axis ? w1y : w1x;
    const float* b1 = axis ? b1y : b1x;
    const float* w2 = axis ? w2y : w2x;

    float4 r = *(const float4*)(refpts + (size_t)bq * 4);
    float ctr  = axis ? r.y : r.x;
    float hlf  = (axis ? r.w : r.z) * 0.5f;
    float lo = (ctr - hlf) * 1024.f;
    float hi = (ctr + hlf) * 1024.f;
    float p  = ((float)pos + 0.5f) * 16.f;
    float d0 = lo - p, d1 = hi - p;

    float a0 = 0.f, a1 = 0.f, a2 = 0.f, a3 = 0.f;
    float a4 = 0.f, a5 = 0.f, a6 = 0.f, a7 = 0.f;

    const int h0 = half * 256;
    #pragma unroll 4
    for (int i = 0; i < 256; ++i) {
        const int hid = h0 + i;
        float hv = fmaf(d0, w1[hid], fmaf(d1, w1[512 + hid], b1[hid]));
        hv = fmaxf(hv, 0.f);
        float4 wA = *(const float4*)(w2 + (size_t)hid * 8);
        float4 wB = *(const float4*)(w2 + (size_t)hid * 8 + 4);
        a0 = fmaf(hv, wA.x, a0); a1 = fmaf(hv, wA.y, a1);
        a2 = fmaf(hv, wA.z, a2); a3 = fmaf(hv, wA.w, a3);
        a4 = fmaf(hv, wB.x, a4); a5 = fmaf(hv, wB.y, a5);
        a6 = fmaf(hv, wB.z, a6); a7 = fmaf(hv, wB.w, a7);
    }
    a0 += __shfl_xor(a0, 1); a1 += __shfl_xor(a1, 1);
    a2 += __shfl_xor(a2, 1); a3 += __shfl_xor(a3, 1);
    a4 += __shfl_xor(a4, 1); a5 += __shfl_xor(a5, 1);
    a6 += __shfl_xor(a6, 1); a7 += __shfl_xor(a7, 1);

    if (half == 0) {
        float* op = (axis ? outy : outx) + (size_t)bq * 512 + pos;
        op[0]   = a0; op[64]  = a1; op[128] = a2; op[192] = a3;
        op[256] = a4; op[320] = a5; op[384] = a6; op[448] = a7;
    }
}

// ---------------------------------------------------------------------------
// Fused flash attention (r1 structure, occupancy-tuned).
// Grid (38, 16): 8 queries x full 4096 keys per block. No split-K, no
// partials: co-resident same-bh blocks stream K/V in lockstep -> L2 reuse
// (r1 measured: FETCH 67 MB, WRITE 0.6 MB). LDS 44 KB -> 3 blocks/CU.
// Phase 1: (qi=t>>5, g=t&31) -> 4 logits; 32-lane shfl reduce.
// Phase 3: slice s3=t>>5 (16 keys); lane (qg1=2q-group of 4, dg) acc[4][2].
// Ks swizzled seg^((kk>>3)&3); VsT swizzled ((kk>>2)^(row>>2&3)) (r7 pattern).
// ---------------------------------------------------------------------------
#define KS_O   0        // Ks  [128][36] -> 4608 (epilogue reduce buf aliases)
#define VST_O  4608     // VsT [32][132] -> 4224
#define PS_O   8832     // Ps  [8][132]  -> 1056
#define RX_O   9888     // Rx  [8][66]   -> 528
#define RY_O   10416    // Ry  [8][66]   -> 528
#define MSK_O  10944    // [128]
#define CF_O   11072    // [8]
#define LV_O   11080    // [8]
#define SM_TOT 11088    // 44352 B

__global__ __launch_bounds__(256, 3) void attn_fused(
    const float* __restrict__ Q,    // [B][300][256] pre-scaled
    const float* __restrict__ K,    // [B][4096][256]
    const float* __restrict__ V,    // [B][4096][256]
    const float* __restrict__ RPX,  // [B*300][8][64]
    const float* __restrict__ RPY,  // [B*300][8][64]
    const float* __restrict__ mask, // [B][4096]
    float* __restrict__ Xout)       // [B][300][256]
{
    __shared__ float sm[SM_TOT];

    const int bh = blockIdx.y;
    const int b  = bh >> 3, h = bh & 7;
    const int q0 = blockIdx.x * QB8;
    const int t  = threadIdx.x;
    const int qi = t >> 5;          // 0..7 (phase 1 query)
    const int g  = t & 31;
    const int s3  = t >> 5;         // 0..7 (phase 3 key slice of 16)
    const int rem = t & 31;
    const int qg1 = rem >> 4;       // 0..1 -> queries qg1*4..+3
    const int dg  = rem & 15;       // dims dg, dg+16

    // Q row -> regs (32 threads sharing qi read the same row: broadcast)
    int qrc = q0 + qi; if (qrc >= NQT) qrc = NQT - 1;
    const float* qp = Q + ((size_t)(b * NQT + qrc)) * 256 + h * HDIM;
    float4 qreg[8];
    #pragma unroll
    for (int c = 0; c < 8; ++c) qreg[c] = *(const float4*)(qp + c * 4);

    // stage Rx, Ry (8 rows x 64)
    for (int i = t; i < QB8 * 64; i += 256) {
        int row = i >> 6, x = i & 63;
        int qr = q0 + row; if (qr >= NQT) qr = NQT - 1;
        size_t base = ((size_t)(b * NQT + qr) * 8 + h) * 64 + x;
        sm[RX_O + row * 66 + x] = RPX[base];
        sm[RY_O + row * 66 + x] = RPY[base];
    }

    float m_r = -1e30f, l_r = 0.f;
    float acc[4][2] = {};

    for (int k0 = 0; k0 < HWT; k0 += TK) {
        __syncthreads();   // prior phase-3 reads (and initial RPE stores) done

        // ---- stage K (seg-swizzled), V^T (col-swizzled), mask ----
        #pragma unroll
        for (int i = 0; i < 4; ++i) {
            int j = t + 256 * i;               // 0..1023
            int kk = j >> 3, seg = j & 7;
            size_t goff = ((size_t)(b * HWT + k0 + kk)) * 256 + h * HDIM + seg * 4;
            float4 kv = *(const float4*)(K + goff);
            float4 vv = *(const float4*)(V + goff);
            int sc = seg ^ ((kk >> 3) & 3);
            *(float4*)&sm[KS_O + kk * 36 + sc * 4] = kv;
            int cb = (((kk >> 2) ^ (seg & 3)) << 2) + (kk & 3);
            sm[VST_O + (seg * 4 + 0) * 132 + cb] = vv.x;
            sm[VST_O + (seg * 4 + 1) * 132 + cb] = vv.y;
            sm[VST_O + (seg * 4 + 2) * 132 + cb] = vv.z;
            sm[VST_O + (seg * 4 + 3) * 132 + cb] = vv.w;
        }
        if (t < TK) sm[MSK_O + t] = mask[(size_t)b * HWT + k0 + t];
        __syncthreads();

        // ---- phase 1: 4 logits + online softmax ----
        float pb[4];
        float tmax = -1e30f;
        #pragma unroll
        for (int u = 0; u < 4; ++u) {
            const int kk = g + 32 * u;
            const int sw = (kk >> 3) & 3;
            const float* kp = &sm[KS_O + kk * 36];
            float dot = 0.f;
            #pragma unroll
            for (int c = 0; c < 8; ++c) {
                float4 kv = *(const float4*)(kp + ((c ^ sw) << 2));
                dot = fmaf(qreg[c].x, kv.x, dot);
                dot = fmaf(qreg[c].y, kv.y, dot);
                dot = fmaf(qreg[c].z, kv.z, dot);
                dot = fmaf(qreg[c].w, kv.w, dot);
            }
            const int kg = k0 + kk;
            float sval = dot + sm[RX_O + qi * 66 + (kg & 63)]
                             + sm[RY_O + qi * 66 + (kg >> 6)]
                             + sm[MSK_O + kk] * (-100.f);
            pb[u] = sval;
            tmax = fmaxf(tmax, sval);
        }
        #pragma unroll
        for (int off = 16; off; off >>= 1)
            tmax = fmaxf(tmax, __shfl_xor(tmax, off));
        const float mn  = fmaxf(m_r, tmax);
        const float cfe = __expf(m_r - mn);
        float psum = 0.f;
        #pragma unroll
        for (int u = 0; u < 4; ++u) {
            float pv = __expf(pb[u] - mn);
            sm[PS_O + qi * 132 + g + 32 * u] = pv;
            psum += pv;
        }
        #pragma unroll
        for (int off = 16; off; off >>= 1)
            psum += __shfl_xor(psum, off);
        l_r = l_r * cfe + psum;
        m_r = mn;
        if (g == 0) sm[CF_O + qi] = cfe;
        __syncthreads();

        // ---- phase 3: PV over this slice's 16 keys, 4q x 2d per lane ----
        float cf0 = sm[CF_O + qg1 * 4 + 0];
        float cf1 = sm[CF_O + qg1 * 4 + 1];
        float cf2 = sm[CF_O + qg1 * 4 + 2];
        float cf3 = sm[CF_O + qg1 * 4 + 3];
        acc[0][0] *= cf0; acc[0][1] *= cf0;
        acc[1][0] *= cf1; acc[1][1] *= cf1;
        acc[2][0] *= cf2; acc[2][1] *= cf2;
        acc[3][0] *= cf3; acc[3][1] *= cf3;

        const int ks0 = s3 * 16;
        #pragma unroll
        for (int kq = 0; kq < 16; kq += 4) {
            const int kk = ks0 + kq;
            const int p4 = (((kk >> 2) ^ ((dg >> 2) & 3)) << 2);   // kk&3==0
            float4 v0 = *(const float4*)&sm[VST_O + dg * 132 + p4];
            float4 v1 = *(const float4*)&sm[VST_O + (dg + 16) * 132 + p4];
            #pragma unroll
            for (int i = 0; i < 4; ++i) {
                float4 pp = *(const float4*)&sm[PS_O + (qg1 * 4 + i) * 132 + kk];
                acc[i][0] = fmaf(pp.x, v0.x, acc[i][0]);
                acc[i][0] = fmaf(pp.y, v0.y, acc[i][0]);
                acc[i][0] = fmaf(pp.z, v0.z, acc[i][0]);
                acc[i][0] = fmaf(pp.w, v0.w, acc[i][0]);
                acc[i][1] = fmaf(pp.x, v1.x, acc[i][1]);
                acc[i][1] = fmaf(pp.y, v1.y, acc[i][1]);
                acc[i][1] = fmaf(pp.z, v1.z, acc[i][1]);
                acc[i][1] = fmaf(pp.w, v1.w, acc[i][1]);
            }
        }
    }

    if (g == 0) sm[LV_O + qi] = l_r;
    __syncthreads();   // all phase-3 reads of Ks region done -> safe to alias

    // cross-slice reduce buffer [8][8*34] aliased over dead Ks
    #pragma unroll
    for (int i = 0; i < 4; ++i) {
        sm[s3 * 272 + (qg1 * 4 + i) * 34 + dg]      = acc[i][0];
        sm[s3 * 272 + (qg1 * 4 + i) * 34 + dg + 16] = acc[i][1];
    }
    __syncthreads();

    {
        const int q = t >> 5, d = t & 31;
        float r = 0.f;
        #pragma unroll
        for (int s = 0; s < 8; ++s) r += sm[s * 272 + q * 34 + d];
        float inv = 1.f / sm[LV_O + q];
        int qrow = q0 + q;
        if (qrow < NQT)
            Xout[((size_t)(b * NQT + qrow)) * 256 + h * HDIM + d] = r * inv;
    }
}

// ---------------------------------------------------------------------------
extern "C" void kernel_launch(void* const* d_in, const int* in_sizes, int n_in,
                              void* d_out, int out_size, void* d_ws, size_t ws_size,
                              hipStream_t stream)
{
    (void)in_sizes; (void)n_in; (void)out_size; (void)ws_size;

    const float* raw_query = (const float*)d_in[0];
    const float* query_pos = (const float*)d_in[1];
    const float* refpts    = (const float*)d_in[2];
    const float* raw_src   = (const float*)d_in[3];
    const float* src_pos   = (const float*)d_in[4];
    const float* mask      = (const float*)d_in[5];
    const float* Wq = (const float*)d_in[7];
    const float* bq = (const float*)d_in[8];
    const float* Wk = (const float*)d_in[9];
    const float* bk = (const float*)d_in[10];
    const float* Wv = (const float*)d_in[11];
    const float* bv = (const float*)d_in[12];
    const float* Wp = (const float*)d_in[13];
    const float* bp = (const float*)d_in[14];
    const float* c1w1 = (const float*)d_in[15];
    const float* c1b1 = (const float*)d_in[16];
    const float* c1w2 = (const float*)d_in[17];
    const float* c2w1 = (const float*)d_in[18];
    const float* c2b1 = (const float*)d_in[19];
    const float* c2w2 = (const float*)d_in[20];

    float* ws = (float*)d_ws;
    float* Qf = ws;                   // 153600
    float* Kf = Qf + 153600;          // 2097152
    float* Vf = Kf + 2097152;         // 2097152
    float* RX = Vf + 2097152;         // 307200
    float* RY = RX + 307200;          // 307200
    float* Xf = RY + 307200;          // 153600

    dim3 blk(256);
    const float qscale = 0.17677669529663687f;  // 32^-0.5

    proj_small<<<dim3(19, 4), blk, 0, stream>>>(raw_query, query_pos, Wq, bq, Qf, 600, qscale);
    proj_kv<<<dim3(512), blk, 0, stream>>>(raw_src, src_pos, Wk, bk, Wv, bv, Kf, Vf);
    rpe_kernel<<<dim3(300, 2), blk, 0, stream>>>(refpts, c1w1, c1b1, c1w2, c2w1, c2b1, c2w2, RX, RY);
    attn_fused<<<dim3(NQB8, 16), blk, 0, stream>>>(Qf, Kf, Vf, RX, RY, mask, Xf);
    proj_small<<<dim3(19, 4), blk, 0, stream>>>(Xf, nullptr, Wp, bp, (float*)d_out, 600, 1.f);
}